// Round 1
// baseline (601.342 us; speedup 1.0000x reference)
//
#include <hip/hip_runtime.h>
#include <hip/hip_bf16.h>

#define T_SEQ 8192
#define E 64
#define BS 128
#define W 256

typedef __attribute__((ext_vector_type(4))) float f32x4;
typedef __attribute__((ext_vector_type(8))) short bf16x8;

__device__ __forceinline__ unsigned short f2bf(float x) {
    union { float f; unsigned u; } v; v.f = x;
    unsigned r = v.u + 0x7fffu + ((v.u >> 16) & 1u);
    return (unsigned short)(r >> 16);
}
__device__ __forceinline__ unsigned pk2(float a, float b) {
    return (unsigned)f2bf(a) | ((unsigned)f2bf(b) << 16);
}

union Frag { unsigned u[4]; bf16x8 v; };

__global__ __launch_bounds__(256, 2)
void la_kernel(const float* __restrict__ q, const float* __restrict__ k,
               const float* __restrict__ v, float* __restrict__ out) {
    __shared__ __align__(16) unsigned short Ks[W * E];   // row-major [j][e], swizzled
    __shared__ __align__(16) unsigned short Vt[E * W];   // transposed [d][j], swizzled

    const int raw  = blockIdx.x;
    // XCD-aware swizzle: consecutive work ids (same bh, adjacent buckets) on same XCD
    const int work = (raw & 7) * 512 + (raw >> 3);
    const int bh = work >> 6;
    const int qb = work & 63;

    const int tid  = threadIdx.x;
    const int wv   = tid >> 6;
    const int lane = tid & 63;
    const int g    = lane >> 4;
    const int col  = lane & 15;

    const size_t base_kv = (size_t)bh * T_SEQ * E;
    const int k0 = (qb - 1) * BS;  // global row index of window start (may be negative)

    // ---- stage K: fp32 global -> bf16 LDS row-major, swizzled ----
    {
        const int jr = tid >> 4;          // 0..15
        const int c4 = (tid & 15) * 4;    // element column base
        #pragma unroll
        for (int t = 0; t < 16; ++t) {
            const int jj = jr + t * 16;
            const int gk = k0 + jj;
            float4 kv = make_float4(0.f, 0.f, 0.f, 0.f);
            if (gk >= 0) kv = *(const float4*)(k + base_kv + (size_t)gk * E + c4);
            uint2 pr;
            pr.x = pk2(kv.x, kv.y);
            pr.y = pk2(kv.z, kv.w);
            const int idx = (jj * 64 + c4) ^ ((jj & 7) << 3);
            *(uint2*)(&Ks[idx]) = pr;
        }
    }

    // ---- stage V: fp32 global -> bf16 LDS transposed [d][j], swizzled ----
    {
        const int d = lane;               // 0..63
        #pragma unroll
        for (int t = 0; t < 32; ++t) {
            const int j  = wv * 2 + t * 8;   // even j, pairs (j, j+1)
            const int gk = k0 + j;
            float a = (gk     >= 0) ? v[base_kv + (size_t)gk * E + d]       : 0.f;
            float b = (gk + 1 >= 0) ? v[base_kv + (size_t)(gk + 1) * E + d] : 0.f;
            const int idx = (d * 256 + j) ^ ((d & 7) << 3);
            *(unsigned*)(&Vt[idx]) = pk2(a, b);
        }
    }

    __syncthreads();

    const int qrow_base = qb * BS + wv * 32;

    #pragma unroll 1
    for (int it = 0; it < 2; ++it) {
        // ---- Q fragments direct from global (B-operand layout) ----
        bf16x8 qf[2];
        #pragma unroll
        for (int kq = 0; kq < 2; ++kq) {
            const float* src = q + ((size_t)bh * T_SEQ + qrow_base + it * 16 + col) * E
                                 + g * 8 + kq * 32;
            float4 f0 = *(const float4*)(src);
            float4 f1 = *(const float4*)(src + 4);
            Frag fr;
            fr.u[0] = pk2(f0.x, f0.y); fr.u[1] = pk2(f0.z, f0.w);
            fr.u[2] = pk2(f1.x, f1.y); fr.u[3] = pk2(f1.z, f1.w);
            qf[kq] = fr.v;
        }

        // ---- S^T = K * Q^T  (M=j, N=i) ----
        f32x4 S[16];
        #pragma unroll
        for (int jt = 0; jt < 16; ++jt) { S[jt][0]=0.f; S[jt][1]=0.f; S[jt][2]=0.f; S[jt][3]=0.f; }
        #pragma unroll
        for (int jt = 0; jt < 16; ++jt) {
            const int j = jt * 16 + col;
            #pragma unroll
            for (int kq = 0; kq < 2; ++kq) {
                const int e   = g * 8 + kq * 32;
                const int idx = (j * 64 + e) ^ ((j & 7) << 3);
                bf16x8 kf = *(const bf16x8*)(&Ks[idx]);
                S[jt] = __builtin_amdgcn_mfma_f32_16x16x32_bf16(kf, qf[kq], S[jt], 0, 0, 0);
            }
        }

        // ---- mask + scale + row max ----
        const int ii = wv * 32 + it * 16 + col;   // query index within bucket
        float mx = -3.0e38f;
        #pragma unroll
        for (int jt = 0; jt < 16; ++jt) {
            #pragma unroll
            for (int r = 0; r < 4; ++r) {
                const int jl = jt * 16 + g * 4 + r;        // key index within window
                const bool ok = (jl <= ii + BS) && (qb > 0 || jl >= BS);
                float s = ok ? S[jt][r] * 0.125f : -1.0e30f;
                S[jt][r] = s;
                mx = fmaxf(mx, s);
            }
        }
        mx = fmaxf(mx, __shfl_xor(mx, 16, 64));
        mx = fmaxf(mx, __shfl_xor(mx, 32, 64));

        // ---- exp + row sum ----
        float sum = 0.f;
        #pragma unroll
        for (int jt = 0; jt < 16; ++jt) {
            #pragma unroll
            for (int r = 0; r < 4; ++r) {
                float p = __expf(S[jt][r] - mx);
                S[jt][r] = p;
                sum += p;
            }
        }
        sum += __shfl_xor(sum, 16, 64);
        sum += __shfl_xor(sum, 32, 64);
        const float inv = 1.0f / sum;

        // ---- PV: O = P * V ----
        f32x4 O[4];
        #pragma unroll
        for (int dt = 0; dt < 4; ++dt) { O[dt][0]=0.f; O[dt][1]=0.f; O[dt][2]=0.f; O[dt][3]=0.f; }

        const int s0 = ((g & 1) << 5) + col;
        const int s1 = s0 + 16;
        const bool hiSel = (g >= 2);

        #pragma unroll
        for (int kt = 0; kt < 8; ++kt) {
            // pack own P^T values (bf16, normalized)
            unsigned x0 = pk2(S[2*kt  ][0] * inv, S[2*kt  ][1] * inv);
            unsigned x1 = pk2(S[2*kt  ][2] * inv, S[2*kt  ][3] * inv);
            unsigned y0 = pk2(S[2*kt+1][0] * inv, S[2*kt+1][1] * inv);
            unsigned y1 = pk2(S[2*kt+1][2] * inv, S[2*kt+1][3] * inv);
            // redistribute into A-fragment layout
            unsigned t0x = (unsigned)__shfl((int)x0, s0, 64), t0y = (unsigned)__shfl((int)y0, s0, 64);
            unsigned t1x = (unsigned)__shfl((int)x1, s0, 64), t1y = (unsigned)__shfl((int)y1, s0, 64);
            unsigned t2x = (unsigned)__shfl((int)x0, s1, 64), t2y = (unsigned)__shfl((int)y0, s1, 64);
            unsigned t3x = (unsigned)__shfl((int)x1, s1, 64), t3y = (unsigned)__shfl((int)y1, s1, 64);
            Frag af;
            af.u[0] = hiSel ? t0y : t0x;
            af.u[1] = hiSel ? t1y : t1x;
            af.u[2] = hiSel ? t2y : t2x;
            af.u[3] = hiSel ? t3y : t3x;

            const int j0 = kt * 32 + g * 8;
            #pragma unroll
            for (int dt = 0; dt < 4; ++dt) {
                const int d   = dt * 16 + col;
                const int idx = (d * 256 + j0) ^ ((d & 7) << 3);
                bf16x8 vf = *(const bf16x8*)(&Vt[idx]);
                O[dt] = __builtin_amdgcn_mfma_f32_16x16x32_bf16(af.v, vf, O[dt], 0, 0, 0);
            }
        }

        // ---- write output (fp32) ----
        #pragma unroll
        for (int dt = 0; dt < 4; ++dt) {
            #pragma unroll
            for (int r = 0; r < 4; ++r) {
                const int row = qrow_base + it * 16 + g * 4 + r;
                const int d   = dt * 16 + col;
                out[((size_t)bh * T_SEQ + row) * E + d] = O[dt][r];
            }
        }
    }
}

extern "C" void kernel_launch(void* const* d_in, const int* in_sizes, int n_in,
                              void* d_out, int out_size, void* d_ws, size_t ws_size,
                              hipStream_t stream) {
    const float* q = (const float*)d_in[0];
    const float* k = (const float*)d_in[1];
    const float* v = (const float*)d_in[2];
    float* out = (float*)d_out;
    la_kernel<<<dim3(64 * 64), dim3(256), 0, stream>>>(q, k, v, out);
}